// Round 1
// baseline (1562.603 us; speedup 1.0000x reference)
//
#include <hip/hip_runtime.h>

#define HEADS 6
#define N_TOK 144
#define DIM   192
#define HD    32
#define NW    64
#define NB    15

#define PAD97  97
#define PAD33  33
#define PAD145 145
#define PAD65  65

// ---------------------------------------------------------------------------
// K0: bias precompute.
// bias_ws[(w*6+h)][i][j] = table[(pos_index[i,j]*64 + w)*6 + h]
// One block per i (144 blocks), 384 threads = (w,h) pairs; gather reads are
// 1536B contiguous per (i,j); each thread streams a contiguous [i*144+j] range.
// ---------------------------------------------------------------------------
__global__ __launch_bounds__(384)
void bias_kernel(const float* __restrict__ table,
                 const int* __restrict__ pos_index,
                 float* __restrict__ bias_ws) {
    int i = blockIdx.x;          // 0..143
    int t = threadIdx.x;         // 0..383 = w*6+h
    for (int j = 0; j < N_TOK; ++j) {
        int idx = pos_index[i * N_TOK + j];
        float v = table[idx * 384 + t];
        bias_ws[(long)t * (N_TOK * N_TOK) + i * N_TOK + j] = v;
    }
}

// ---------------------------------------------------------------------------
// K1: fused per-(b,w,head) attention.
// Phase 1: q,k,v[144,32] = x[144,192] @ qkv_w_head^T (two 96-col passes in LDS)
// Phase 2: attn[144,144] = q k^T + bias + mask
// Phase 3: row softmax
// Phase 4: out = attn @ v -> tmp[b,w,n, head*32+d]
// ---------------------------------------------------------------------------
__global__ __launch_bounds__(384)
void attn_kernel(const float* __restrict__ x,
                 const float* __restrict__ mask,
                 const float* __restrict__ qkv_w,
                 const float* __restrict__ qkv_b,
                 const float* __restrict__ bias_ws,
                 float* __restrict__ tmp) {
    __shared__ float qkv[3][N_TOK * PAD33];                 // 57,024 B
    __shared__ union U {
        struct { float xs[N_TOK * PAD97]; float ws[96 * PAD97]; } p1; // 93,120 B
        float attn[N_TOK * PAD145];                          // 83,520 B
    } u;                                                     // total 150,144 B

    const int tid  = threadIdx.x;
    const int bid  = blockIdx.x;
    const int head = bid % HEADS;
    const int w    = (bid / HEADS) % NW;
    const int b    = bid / (HEADS * NW);
    const float scale = 0.17677669529663687f;  // 32^-0.5

    const long xbase = ((long)(b * NW + w) * N_TOK) * DIM;

    // ---- Phase 1: qkv projection for this head ----
    const int tn = tid & 15;    // 0..15 (n-group)
    const int td = tid >> 4;    // 0..23 (dd-group)
    float acc[9][4] = {};

    for (int p = 0; p < 2; ++p) {
        const int c0 = p * 96;
        __syncthreads();  // previous pass's readers done with xs/ws
        for (int tt = tid; tt < N_TOK * 96; tt += 384) {
            int n = tt / 96, c = tt - n * 96;
            u.p1.xs[n * PAD97 + c] = x[xbase + n * DIM + c0 + c];
        }
        for (int tt = tid; tt < 96 * 96; tt += 384) {
            int dd = tt / 96, c = tt - dd * 96;
            int row = (dd >> 5) * DIM + head * HD + (dd & 31);
            u.p1.ws[dd * PAD97 + c] = qkv_w[row * DIM + c0 + c];
        }
        __syncthreads();
        for (int c = 0; c < 96; ++c) {
            float xv[9], wv[4];
            #pragma unroll
            for (int i = 0; i < 9; ++i) xv[i] = u.p1.xs[(tn * 9 + i) * PAD97 + c];
            #pragma unroll
            for (int jj = 0; jj < 4; ++jj) wv[jj] = u.p1.ws[(td * 4 + jj) * PAD97 + c];
            #pragma unroll
            for (int i = 0; i < 9; ++i)
                #pragma unroll
                for (int jj = 0; jj < 4; ++jj)
                    acc[i][jj] += xv[i] * wv[jj];
        }
    }

    // write q,k,v to LDS (distinct region from xs/ws)
    #pragma unroll
    for (int i = 0; i < 9; ++i) {
        int n = tn * 9 + i;
        #pragma unroll
        for (int jj = 0; jj < 4; ++jj) {
            int dd = td * 4 + jj;
            int sel = dd >> 5, e = dd & 31;
            float val = acc[i][jj] + qkv_b[sel * DIM + head * HD + e];
            if (sel == 0) val *= scale;
            qkv[sel][n * PAD33 + e] = val;
        }
    }
    __syncthreads();  // qkv visible; xs/ws readers done -> attn region reusable

    // ---- Phase 2: attn = q k^T + bias + mask ----
    {
        const int ti = tid & 15;   // i-group
        const int tj = tid >> 4;   // 0..23 j-group
        float a2[9][6] = {};
        for (int e = 0; e < HD; ++e) {
            float qv[9], kv[6];
            #pragma unroll
            for (int i = 0; i < 9; ++i) qv[i] = qkv[0][(ti * 9 + i) * PAD33 + e];
            #pragma unroll
            for (int jj = 0; jj < 6; ++jj) kv[jj] = qkv[1][(tj * 6 + jj) * PAD33 + e];
            #pragma unroll
            for (int i = 0; i < 9; ++i)
                #pragma unroll
                for (int jj = 0; jj < 6; ++jj)
                    a2[i][jj] += qv[i] * kv[jj];
        }
        const float* maskp = mask + (long)(b * NW + w) * (N_TOK * N_TOK);
        const float* biasp = bias_ws + (long)(w * HEADS + head) * (N_TOK * N_TOK);
        #pragma unroll
        for (int i = 0; i < 9; ++i) {
            int ii = ti * 9 + i;
            #pragma unroll
            for (int jj = 0; jj < 6; ++jj) {
                int jx = tj * 6 + jj;
                u.attn[ii * PAD145 + jx] =
                    a2[i][jj] + biasp[ii * N_TOK + jx] + maskp[ii * N_TOK + jx];
            }
        }
    }
    __syncthreads();

    // ---- Phase 3: row softmax (threads 0..143 each own a row) ----
    if (tid < N_TOK) {
        float m = -1e30f;
        for (int j = 0; j < N_TOK; ++j)
            m = fmaxf(m, u.attn[tid * PAD145 + j]);
        float s = 0.f;
        for (int j = 0; j < N_TOK; ++j) {
            float e_ = __expf(u.attn[tid * PAD145 + j] - m);
            u.attn[tid * PAD145 + j] = e_;
            s += e_;
        }
        float inv = 1.f / s;
        for (int j = 0; j < N_TOK; ++j)
            u.attn[tid * PAD145 + j] *= inv;
    }
    __syncthreads();

    // ---- Phase 4: out = attn @ v ----
    {
        const int tn2 = tid % 48;   // n-group
        const int td2 = tid / 48;   // 0..7 d-group
        float o[3][4] = {};
        for (int j = 0; j < N_TOK; ++j) {
            float av[3], vv[4];
            #pragma unroll
            for (int i = 0; i < 3; ++i) av[i] = u.attn[(tn2 * 3 + i) * PAD145 + j];
            #pragma unroll
            for (int jj = 0; jj < 4; ++jj) vv[jj] = qkv[2][j * PAD33 + td2 * 4 + jj];
            #pragma unroll
            for (int i = 0; i < 3; ++i)
                #pragma unroll
                for (int jj = 0; jj < 4; ++jj)
                    o[i][jj] += av[i] * vv[jj];
        }
        float* outp = tmp + xbase;
        #pragma unroll
        for (int i = 0; i < 3; ++i) {
            int n = tn2 * 3 + i;
            #pragma unroll
            for (int jj = 0; jj < 4; ++jj) {
                int d = td2 * 4 + jj;
                outp[n * DIM + head * HD + d] = o[i][jj];
            }
        }
    }
}

// ---------------------------------------------------------------------------
// K2: output projection. One block per (b,w): [144,192] @ proj_w^T + proj_b.
// K split into 3 x 64, both operands LDS-staged, 9x8 register tile per thread.
// ---------------------------------------------------------------------------
__global__ __launch_bounds__(384)
void proj_kernel(const float* __restrict__ tmp,
                 const float* __restrict__ proj_w,
                 const float* __restrict__ proj_b,
                 float* __restrict__ out) {
    __shared__ float in_lds[N_TOK * PAD65];  // 37,440 B
    __shared__ float w_lds[DIM * PAD65];     // 49,920 B

    const int tid = threadIdx.x;
    const long base = (long)blockIdx.x * (N_TOK * DIM);
    const int tn = tid & 15;   // 0..15 (n-group)
    const int td = tid >> 4;   // 0..23 (d-group)
    float acc[9][8] = {};

    for (int p = 0; p < 3; ++p) {
        const int c0 = p * 64;
        __syncthreads();
        for (int tt = tid; tt < N_TOK * 64; tt += 384) {
            int n = tt >> 6, c = tt & 63;
            in_lds[n * PAD65 + c] = tmp[base + n * DIM + c0 + c];
        }
        for (int tt = tid; tt < DIM * 64; tt += 384) {
            int d = tt >> 6, c = tt & 63;
            w_lds[d * PAD65 + c] = proj_w[d * DIM + c0 + c];
        }
        __syncthreads();
        for (int c = 0; c < 64; ++c) {
            float iv[9], wv[8];
            #pragma unroll
            for (int i = 0; i < 9; ++i) iv[i] = in_lds[(tn * 9 + i) * PAD65 + c];
            #pragma unroll
            for (int jj = 0; jj < 8; ++jj) wv[jj] = w_lds[(td * 8 + jj) * PAD65 + c];
            #pragma unroll
            for (int i = 0; i < 9; ++i)
                #pragma unroll
                for (int jj = 0; jj < 8; ++jj)
                    acc[i][jj] += iv[i] * wv[jj];
        }
    }

    #pragma unroll
    for (int i = 0; i < 9; ++i) {
        int n = tn * 9 + i;
        #pragma unroll
        for (int jj = 0; jj < 8; ++jj) {
            int d = td * 8 + jj;
            out[base + n * DIM + d] = acc[i][jj] + proj_b[d];
        }
    }
}

// ---------------------------------------------------------------------------
extern "C" void kernel_launch(void* const* d_in, const int* in_sizes, int n_in,
                              void* d_out, int out_size, void* d_ws, size_t ws_size,
                              hipStream_t stream) {
    const float* x        = (const float*)d_in[0];
    const float* mask     = (const float*)d_in[1];
    const float* qkv_w    = (const float*)d_in[2];
    const float* qkv_b    = (const float*)d_in[3];
    const float* table    = (const float*)d_in[4];
    const float* proj_w   = (const float*)d_in[5];
    const float* proj_b   = (const float*)d_in[6];
    const int*   pos_index= (const int*)d_in[7];
    float* out = (float*)d_out;

    // workspace layout: bias_ws [384 * 144*144] f32 (31.85 MB), then
    // tmp [15*64*144*192] f32 (106.2 MB). total ~138 MB.
    float* bias_ws = (float*)d_ws;
    float* tmp     = bias_ws + (size_t)384 * N_TOK * N_TOK;

    bias_kernel<<<N_TOK, 384, 0, stream>>>(table, pos_index, bias_ws);
    attn_kernel<<<NB * NW * HEADS, 384, 0, stream>>>(x, mask, qkv_w, qkv_b,
                                                     bias_ws, tmp);
    proj_kernel<<<NB * NW, 384, 0, stream>>>(tmp, proj_w, proj_b, out);
}

// Round 2
// 573.049 us; speedup vs baseline: 2.7268x; 2.7268x over previous
//
#include <hip/hip_runtime.h>

#define HEADS 6
#define N_TOK 144
#define DIM   192
#define NW    64
#define NB    15
#define NBW   (NB * NW)          // 960
#define CHUNK 480                // bw per chunk (2 chunks)

typedef __attribute__((ext_vector_type(8))) short bf16x8;
typedef __attribute__((ext_vector_type(4))) float f32x4;

#define MFMA(a, b, c) __builtin_amdgcn_mfma_f32_16x16x32_bf16(a, b, c, 0, 0, 0)

static __device__ __forceinline__ short f2bf(float f) {
    union { float f; unsigned u; } v; v.f = f;
    unsigned r = v.u + 0x7FFFu + ((v.u >> 16) & 1u);   // RNE
    return (short)(r >> 16);
}
static __device__ __forceinline__ float bf2f(short s) {
    union { unsigned u; float f; } v;
    v.u = ((unsigned)(unsigned short)s) << 16;
    return v.f;
}

// ---------------------------------------------------------------------------
// K0a: bias gather -> bf16, layout [(w*6+h)][i*144+j]. Block per (w,h):
// coalesced writes, gathered table reads stay in L2 (table = 5.1 MB).
// ---------------------------------------------------------------------------
__global__ __launch_bounds__(256)
void bias_k(const float* __restrict__ table, const int* __restrict__ pos_index,
            short* __restrict__ bias_bf) {
    const int t = blockIdx.x;                      // w*6+h, 0..383
    for (int e = threadIdx.x; e < N_TOK * N_TOK; e += 256) {
        int idx = pos_index[e];
        bias_bf[(long)t * (N_TOK * N_TOK) + e] = f2bf(table[(long)idx * 384 + t]);
    }
}

// K0b: f32 -> bf16 copy (proj_w)
__global__ __launch_bounds__(256)
void cvt_k(const float* __restrict__ w, short* __restrict__ o, int n) {
    int i = blockIdx.x * 256 + threadIdx.x;
    if (i < n) o[i] = f2bf(w[i]);
}

// ---------------------------------------------------------------------------
// K1: QKV projection GEMM, block = (bwL, sel). W_sel staged to LDS as bf16
// (stride 200 bf16 = 100 dw == 4 mod 32 -> 2-way, free). 9 waves = 3 M-groups
// x 3 N-groups; wave: 3 M-tiles x 4 N-tiles, K = 6 steps of 32.
// Output bf16: qkv_ws[((bwL*6+h)*3+sel)][row][e], q pre-scaled.
// ---------------------------------------------------------------------------
__global__ __launch_bounds__(576)
void qkv_k(const float* __restrict__ x, const float* __restrict__ qkv_w,
           const float* __restrict__ qkv_b, short* __restrict__ qkv_out,
           int bw0) {
    __shared__ short wlds[192 * 200];
    const int bid = blockIdx.x;
    const int sel = bid % 3;
    const int bwL = bid / 3;
    const int bwG = bw0 + bwL;
    const int tid = threadIdx.x;

    for (int u = tid; u < 192 * 192; u += 576) {
        int r = u / 192, c = u - r * 192;
        wlds[r * 200 + c] = f2bf(qkv_w[(sel * 192 + r) * 192 + c]);
    }
    __syncthreads();

    const int wid = tid >> 6, lane = tid & 63, lq = lane & 15, lg = lane >> 4;
    const int mg = wid / 3, ng = wid % 3;
    const float* xb = x + (long)bwG * N_TOK * DIM;

    f32x4 acc[3][4] = {};
    for (int ks = 0; ks < 6; ++ks) {
        const int k0 = ks * 32 + 8 * lg;
        bf16x8 av[3], bv[4];
        #pragma unroll
        for (int mt = 0; mt < 3; ++mt) {
            const float4* p = (const float4*)(xb + (mg * 48 + mt * 16 + lq) * DIM + k0);
            float4 f0 = p[0], f1 = p[1];
            bf16x8 a;
            a[0] = f2bf(f0.x); a[1] = f2bf(f0.y); a[2] = f2bf(f0.z); a[3] = f2bf(f0.w);
            a[4] = f2bf(f1.x); a[5] = f2bf(f1.y); a[6] = f2bf(f1.z); a[7] = f2bf(f1.w);
            av[mt] = a;
        }
        #pragma unroll
        for (int nt = 0; nt < 4; ++nt)
            bv[nt] = *(const bf16x8*)&wlds[(ng * 64 + nt * 16 + lq) * 200 + k0];
        #pragma unroll
        for (int mt = 0; mt < 3; ++mt)
            #pragma unroll
            for (int nt = 0; nt < 4; ++nt)
                acc[mt][nt] = MFMA(av[mt], bv[nt], acc[mt][nt]);
    }

    const float scale = 0.17677669529663687f;   // 32^-0.5
    #pragma unroll
    for (int nt = 0; nt < 4; ++nt) {
        const int cd = ng * 64 + nt * 16 + lq;          // channel 0..191
        const float bb = qkv_b[sel * 192 + cd];
        const int h = cd >> 5, e = cd & 31;
        short* ob = qkv_out + ((long)(bwL * 6 + h) * 3 + sel) * 4608 + e;
        #pragma unroll
        for (int mt = 0; mt < 3; ++mt)
            #pragma unroll
            for (int i = 0; i < 4; ++i) {
                int row = mg * 48 + mt * 16 + 4 * lg + i;
                float v = acc[mt][nt][i] + bb;
                if (sel == 0) v *= scale;
                ob[row * 32] = f2bf(v);
            }
    }
}

// ---------------------------------------------------------------------------
// K2: attention, block = (bwL, head), 9 waves, wave = 16 query rows.
// QK^T: A=q, B=k direct 16B global loads (K=32, one MFMA step).
// softmax in regs (rows 4g+i per lane, shfl_xor over 16-lane col group).
// P -> LDS (per-wave, stride 152 -> 2-way free). v transposed to LDS once.
// PV: 2 N-tiles x 5 K-steps, tail step masks lanes lg>=2 (keys >=144).
// ---------------------------------------------------------------------------
__global__ __launch_bounds__(576)
void attn_k(const short* __restrict__ qkv, const short* __restrict__ bias_bf,
            const float* __restrict__ mask, short* __restrict__ tmp, int bw0) {
    __shared__ short shmem[9 * 16 * 152 + 32 * 152 + 128];
    short* plds = shmem;                 // 9 waves x [16][152]
    short* vlds = shmem + 9 * 16 * 152;  // [32][152] (+128 slack at end)

    const int bid = blockIdx.x;
    const int h   = bid % 6;
    const int bwL = bid / 6;
    const int bwG = bw0 + bwL;
    const int tid = threadIdx.x;

    const short* qb = qkv + ((long)(bwL * 6 + h) * 3) * 4608;
    const short* kb = qb + 4608;
    const short* vb = qb + 9216;

    // stage v transposed: vlds[e][j] = v[j][e]
    {
        int j = tid >> 2, e0 = (tid & 3) * 8;
        bf16x8 vv = *(const bf16x8*)&vb[j * 32 + e0];
        #pragma unroll
        for (int u = 0; u < 8; ++u) vlds[(e0 + u) * 152 + j] = vv[u];
    }
    __syncthreads();

    const int lane = tid & 63, lq = lane & 15, lg = lane >> 4;
    const int wid = tid >> 6;
    const int m0 = wid * 16;

    // ---- QK^T ----
    const f32x4 zf = {};
    bf16x8 aq = *(const bf16x8*)&qb[(m0 + lq) * 32 + 8 * lg];
    f32x4 lgt[9];
    #pragma unroll
    for (int nt = 0; nt < 9; ++nt) {
        bf16x8 bk = *(const bf16x8*)&kb[(nt * 16 + lq) * 32 + 8 * lg];
        lgt[nt] = MFMA(aq, bk, zf);
    }

    // ---- + bias + mask ----
    const int w = bwG & 63;
    const short* bp = bias_bf + (long)(w * 6 + h) * (N_TOK * N_TOK);
    const float* mp = mask + (long)bwG * (N_TOK * N_TOK);
    #pragma unroll
    for (int nt = 0; nt < 9; ++nt)
        #pragma unroll
        for (int i = 0; i < 4; ++i) {
            int r = m0 + 4 * lg + i, c = nt * 16 + lq;
            lgt[nt][i] += bf2f(bp[r * N_TOK + c]) + mp[r * N_TOK + c];
        }

    // ---- softmax (rows 4*lg+i) ----
    float inv_s[4];
    #pragma unroll
    for (int i = 0; i < 4; ++i) {
        float m = lgt[0][i];
        #pragma unroll
        for (int nt = 1; nt < 9; ++nt) m = fmaxf(m, lgt[nt][i]);
        m = fmaxf(m, __shfl_xor(m, 1));
        m = fmaxf(m, __shfl_xor(m, 2));
        m = fmaxf(m, __shfl_xor(m, 4));
        m = fmaxf(m, __shfl_xor(m, 8));
        float s = 0.f;
        #pragma unroll
        for (int nt = 0; nt < 9; ++nt) {
            float p = __expf(lgt[nt][i] - m);
            lgt[nt][i] = p;
            s += p;
        }
        s += __shfl_xor(s, 1);
        s += __shfl_xor(s, 2);
        s += __shfl_xor(s, 4);
        s += __shfl_xor(s, 8);
        inv_s[i] = 1.f / s;
    }

    // ---- P -> LDS (per-wave region; same-wave consume, no barrier) ----
    short* pw = plds + wid * 16 * 152;
    #pragma unroll
    for (int nt = 0; nt < 9; ++nt)
        #pragma unroll
        for (int i = 0; i < 4; ++i)
            pw[(4 * lg + i) * 152 + nt * 16 + lq] = f2bf(lgt[nt][i]);

    // ---- PV ----
    f32x4 o[2] = {};
    const bf16x8 zb = {};
    #pragma unroll
    for (int ks = 0; ks < 5; ++ks) {
        bf16x8 ap = *(const bf16x8*)&pw[lq * 152 + ks * 32 + 8 * lg];
        #pragma unroll
        for (int nt = 0; nt < 2; ++nt) {
            bf16x8 bv = *(const bf16x8*)&vlds[(nt * 16 + lq) * 152 + ks * 32 + 8 * lg];
            if (ks == 4 && lg >= 2) { ap = zb; bv = zb; }   // keys 144..159
            o[nt] = MFMA(ap, bv, o[nt]);
        }
    }

    // ---- normalize, write tmp bf16 [bwL][row][h*32+e] ----
    short* ob = tmp + (long)bwL * N_TOK * DIM + h * 32;
    #pragma unroll
    for (int nt = 0; nt < 2; ++nt)
        #pragma unroll
        for (int i = 0; i < 4; ++i) {
            int row = m0 + 4 * lg + i;
            ob[row * DIM + nt * 16 + lq] = f2bf(o[nt][i] * inv_s[i]);
        }
}

// ---------------------------------------------------------------------------
// K3: output projection, block = (bwL, m-third), 3 waves, wave = 16 rows.
// A from tmp bf16 (16B loads), B from L2-resident bf16 proj_w. No LDS.
// ---------------------------------------------------------------------------
__global__ __launch_bounds__(192)
void proj_k(const short* __restrict__ tmp, const short* __restrict__ pwt,
            const float* __restrict__ proj_b, float* __restrict__ out, int bw0) {
    const int bid = blockIdx.x;
    const int mthird = bid % 3;
    const int bwL = bid / 3;
    const int bwG = bw0 + bwL;
    const int tid = threadIdx.x;
    const int wid = tid >> 6, lane = tid & 63, lq = lane & 15, lg = lane >> 4;
    const int m0 = (mthird * 3 + wid) * 16;
    const short* tb = tmp + (long)bwL * N_TOK * DIM;

    f32x4 acc[12] = {};
    for (int ks = 0; ks < 6; ++ks) {
        const int k0 = ks * 32 + 8 * lg;
        bf16x8 a = *(const bf16x8*)&tb[(m0 + lq) * DIM + k0];
        #pragma unroll
        for (int nt = 0; nt < 12; ++nt) {
            bf16x8 b = *(const bf16x8*)&pwt[(nt * 16 + lq) * DIM + k0];
            acc[nt] = MFMA(a, b, acc[nt]);
        }
    }
    float* ob = out + (long)bwG * N_TOK * DIM;
    #pragma unroll
    for (int nt = 0; nt < 12; ++nt) {
        float pb = proj_b[nt * 16 + lq];
        #pragma unroll
        for (int i = 0; i < 4; ++i)
            ob[(m0 + 4 * lg + i) * DIM + nt * 16 + lq] = acc[nt][i] + pb;
    }
}

// ---------------------------------------------------------------------------
extern "C" void kernel_launch(void* const* d_in, const int* in_sizes, int n_in,
                              void* d_out, int out_size, void* d_ws, size_t ws_size,
                              hipStream_t stream) {
    const float* x        = (const float*)d_in[0];
    const float* mask     = (const float*)d_in[1];
    const float* qkv_w    = (const float*)d_in[2];
    const float* qkv_b    = (const float*)d_in[3];
    const float* table    = (const float*)d_in[4];
    const float* proj_w   = (const float*)d_in[5];
    const float* proj_b   = (const float*)d_in[6];
    const int*   pos_index= (const int*)d_in[7];
    float* out = (float*)d_out;

    // ws layout (bf16 shorts), total ~122.2 MB:
    //  bias_bf  [384][144*144]                 15.93 MB
    //  projw_bf [192*192]                       0.07 MB
    //  qkv_ws   [CHUNK*6 x 3 x 144 x 32]       79.63 MB  (reused per chunk)
    //  tmp_ws   [CHUNK x 144 x 192]            26.54 MB  (reused per chunk)
    short* bias_bf  = (short*)d_ws;
    short* projw_bf = bias_bf + (size_t)384 * N_TOK * N_TOK;
    short* qkv_ws   = projw_bf + 36864;
    short* tmp_ws   = qkv_ws + (size_t)CHUNK * 6 * 3 * 4608;

    bias_k<<<384, 256, 0, stream>>>(table, pos_index, bias_bf);
    cvt_k<<<144, 256, 0, stream>>>(proj_w, projw_bf, DIM * DIM);

    for (int c = 0; c < 2; ++c) {
        const int bw0 = c * CHUNK;
        qkv_k<<<CHUNK * 3, 576, 0, stream>>>(x, qkv_w, qkv_b, qkv_ws, bw0);
        attn_k<<<CHUNK * 6, 576, 0, stream>>>(qkv_ws, bias_bf, mask, tmp_ws, bw0);
        proj_k<<<CHUNK * 3, 192, 0, stream>>>(tmp_ws, projw_bf, proj_b, out, bw0);
    }
}